// Round 1
// baseline (91.988 us; speedup 1.0000x reference)
//
#include <hip/hip_runtime.h>

// Tropical (max-plus) linear layer:
//   out[b, j] = max_k (x[b,k] + w[j,k]) + bias[j]   if any product > -1e38
//             = -1e38                                otherwise
// x: [4096, 256] f32, w: [256, 256] f32, bias: [256] f32, out: [4096, 256] f32
//
// R4 structure: w-resident-in-VGPR, k-split across waves.
//  - Pure-VALU problem (no MFMA for (max,+) semiring). Floor ~5.1 us.
//  - Previous version mixed ds_read (w) + s_load (x) in the inner loop ->
//    lgkmcnt(0) drains every k4 step (SMEM completes OOO vs DS) -> ~17% VALU.
//  - Now: wave = k-quarter. w[col0+lane, kq*64..+63] loaded ONCE into 64 VGPRs.
//    Hot loop per row: batched wave-uniform s_loads of x (one lgkm wait) +
//    96 VALU (4 v_add + 2 v_max3 per k4) + 1 conflict-free ds_write_b32.
//    No barriers until the final 4-way combine.
//  - Grid (256,4) = 1024 blocks = 4 blocks/CU = 16 waves/CU; VGPR ~90 <= 128.

#define TZERO -1e38f

constexpr int K    = 256;
constexpr int N    = 256;
constexpr int ROWS = 16;   // rows per block
constexpr int NT   = 256;  // 4 waves = 4 k-quarters

__global__ __launch_bounds__(NT, 4)
void tropical_kernel(const float* __restrict__ x, const float* __restrict__ w,
                     const float* __restrict__ bias, float* __restrict__ out)
{
    __shared__ float part[4][ROWS][64];   // per-kq partial maxima, 16 KB

    const int t    = threadIdx.x;
    const int lane = t & 63;
    const int kq   = __builtin_amdgcn_readfirstlane(t >> 6);  // wave = k-quarter
    const int row0 = blockIdx.x * ROWS;
    const int col0 = blockIdx.y * 64;

    // ---- load this wave's w slice once: w[col0+lane, kq*64 .. kq*64+63]
    //      16 float4 = 64 VGPRs, statically indexed everywhere below.
    const float* wsrc = w + (size_t)(col0 + lane) * K + kq * 64;
    float4 wq[16];
#pragma unroll
    for (int i = 0; i < 16; ++i)
        wq[i] = *reinterpret_cast<const float4*>(wsrc + 4 * i);

    // bias for the epilogue (per-lane, hoisted ahead of the main loop)
    const float bj = bias[col0 + lane];

    // ---- main loop: one x row-chunk per iteration, all wave-uniform loads
    const float* xbase = x + (size_t)row0 * K + kq * 64;

#pragma unroll 2
    for (int r = 0; r < ROWS; ++r) {
        const float* xr = xbase + (size_t)r * K;
        // two independent accumulators: halves the v_max3 dependency chain
        float m0 = -__builtin_inff();
        float m1 = -__builtin_inff();
#pragma unroll
        for (int i = 0; i < 16; ++i) {
            // wave-uniform address -> scalar (SMEM) load path, batched by
            // the compiler into s_load_dwordx8/x16 with a single lgkm wait
            const float4 xv = *reinterpret_cast<const float4*>(xr + 4 * i);
            const float t0 = xv.x + wq[i].x;
            const float t1 = xv.y + wq[i].y;
            const float t2 = xv.z + wq[i].z;
            const float t3 = xv.w + wq[i].w;
            if (i & 1) {
                m1 = fmaxf(fmaxf(m1, t0), t1);   // v_max3_f32
                m1 = fmaxf(fmaxf(m1, t2), t3);   // v_max3_f32
            } else {
                m0 = fmaxf(fmaxf(m0, t0), t1);
                m0 = fmaxf(fmaxf(m0, t2), t3);
            }
        }
        // [kq][r][lane]: lanes hit consecutive banks -> 2-way alias, free
        part[kq][r][lane] = fmaxf(m0, m1);
    }

    __syncthreads();

    // ---- epilogue: 4-way combine across k-quarters, bias, guard, store
    const int er0 = (t >> 6) * 4;   // each wave finishes 4 rows
#pragma unroll
    for (int i = 0; i < 4; ++i) {
        const int r = er0 + i;
        const float v = fmaxf(fmaxf(part[0][r][lane], part[1][r][lane]),
                              fmaxf(part[2][r][lane], part[3][r][lane]));
        out[(size_t)(row0 + r) * N + col0 + lane] = (v > TZERO) ? v + bj : TZERO;
    }
}

extern "C" void kernel_launch(void* const* d_in, const int* in_sizes, int n_in,
                              void* d_out, int out_size, void* d_ws, size_t ws_size,
                              hipStream_t stream) {
    const float* x  = (const float*)d_in[0];
    const float* w  = (const float*)d_in[1];
    const float* b  = (const float*)d_in[2];
    float* out      = (float*)d_out;

    dim3 grid(4096 / ROWS, N / 64);   // (256, 4) = 1024 blocks, 4 waves each
    tropical_kernel<<<grid, NT, 0, stream>>>(x, w, b, out);
}

// Round 2
// 74.276 us; speedup vs baseline: 1.2385x; 1.2385x over previous
//
#include <hip/hip_runtime.h>

// Tropical (max-plus) linear layer:
//   out[b, j] = max_k (x[b,k] + w[j,k]) + bias[j]   if any product > -1e38
//             = -1e38                                otherwise
// x: [4096, 256] f32, w: [256, 256] f32, bias: [256] f32, out: [4096, 256] f32
//
// R5 structure: w-in-VGPR + LDS-broadcast x. Pure-VALU floor ~5.1 us.
//  - R4 post-mortem: x-via-SGPR path blew the SGPR budget (112 SGPRs) and
//    spilled wq to scratch (VGPR_Count=64 < needed, WRITE_SIZE=44MB) -> 149us.
//  - R5: 8 waves = 8 k-segments of 32. Lane owns 2 cols; w slice = 16 float4
//    = 64 VGPRs, statically indexed. x tile staged once in LDS; hot loop reads
//    x with wave-uniform ds_read_b128 (broadcast, conflict-free, no SGPRs).
//    Ratio: 1 ds_read_b128 : 12 VALU (4 v_add + 2 v_max3 per col).
//  - No barriers in the main loop; per-row partials to LDS; 2-phase combine
//    (row halves) keeps LDS at 16KB x + 32KB part = 48KB < 64KB static limit.
//  - ~100 VGPR < 128 cap (launch_bounds(512,4)) -> 16 waves/CU, 4/SIMD.

#define TZERO -1e38f

constexpr int K    = 256;
constexpr int N    = 256;
constexpr int ROWS = 16;    // rows per block
constexpr int COLS = 128;   // cols per block (2 per lane)
constexpr int NT   = 512;   // 8 waves
constexpr int KSEG = 32;    // k-extent per wave
constexpr int HR   = ROWS / 2;

__global__ __launch_bounds__(NT, 4)
void tropical_kernel(const float* __restrict__ x, const float* __restrict__ w,
                     const float* __restrict__ bias, float* __restrict__ out)
{
    __shared__ float xs[ROWS][K];        // 16 KB, read-only after staging
    __shared__ float part[8][HR][COLS];  // 32 KB, reused per row-half

    const int t    = threadIdx.x;
    const int lane = t & 63;
    const int ws   = __builtin_amdgcn_readfirstlane(t >> 6);  // k-segment id
    const int row0 = blockIdx.x * ROWS;
    const int col0 = blockIdx.y * COLS;

    // ---- w fragments: 2 cols x 32 k = 16 float4 = 64 VGPRs, static indexing
    const float* w0 = w + (size_t)(col0 + lane) * K + ws * KSEG;
    const float* w1 = w0 + (size_t)64 * K;
    float4 wA[8], wB[8];
#pragma unroll
    for (int i = 0; i < 8; ++i) {
        wA[i] = *reinterpret_cast<const float4*>(w0 + 4 * i);
        wB[i] = *reinterpret_cast<const float4*>(w1 + 4 * i);
    }

    // ---- stage x tile (contiguous 16 KB): 2 coalesced float4 per thread
    {
        const float4* xsrc = reinterpret_cast<const float4*>(x + (size_t)row0 * K);
        float4* xdst = reinterpret_cast<float4*>(&xs[0][0]);
        xdst[t]      = xsrc[t];
        xdst[t + NT] = xsrc[t + NT];
    }
    __syncthreads();

    for (int half = 0; half < 2; ++half) {
        // ---- main loop: per row, 8 broadcast ds_read_b128 + 96 VALU
        for (int r = 0; r < HR; ++r) {
            const int rr = half * HR + r;
            const float* xrow = &xs[rr][ws * KSEG];
            float a0 = -__builtin_inff();
            float a1 = -__builtin_inff();
#pragma unroll
            for (int i = 0; i < 8; ++i) {
                // wave-uniform LDS address -> broadcast, conflict-free
                const float4 xv = *reinterpret_cast<const float4*>(xrow + 4 * i);
                const float s0 = xv.x + wA[i].x;
                const float s1 = xv.y + wA[i].y;
                const float s2 = xv.z + wA[i].z;
                const float s3 = xv.w + wA[i].w;
                a0 = fmaxf(fmaxf(a0, s0), s1);   // v_max3_f32
                a0 = fmaxf(fmaxf(a0, s2), s3);   // v_max3_f32
                const float u0 = xv.x + wB[i].x;
                const float u1 = xv.y + wB[i].y;
                const float u2 = xv.z + wB[i].z;
                const float u3 = xv.w + wB[i].w;
                a1 = fmaxf(fmaxf(a1, u0), u1);
                a1 = fmaxf(fmaxf(a1, u2), u3);
            }
            part[ws][r][lane]      = a0;   // consecutive banks, free
            part[ws][r][64 + lane] = a1;
        }
        __syncthreads();

        // ---- combine: 8 rows x 128 cols = 1024 outputs, 2 per thread
        {
            const int c  = t & 127;
            const int rb = t >> 7;             // 0..3
            const float bj = bias[col0 + c];
#pragma unroll
            for (int j = 0; j < 2; ++j) {
                const int r = rb + 4 * j;
                float v = part[0][r][c];
#pragma unroll
                for (int s = 1; s < 8; ++s) v = fmaxf(v, part[s][r][c]);
                out[(size_t)(row0 + half * HR + r) * N + col0 + c] =
                    (v > TZERO) ? v + bj : TZERO;
            }
        }
        __syncthreads();   // part may be overwritten by next half
    }
}

extern "C" void kernel_launch(void* const* d_in, const int* in_sizes, int n_in,
                              void* d_out, int out_size, void* d_ws, size_t ws_size,
                              hipStream_t stream) {
    const float* x  = (const float*)d_in[0];
    const float* w  = (const float*)d_in[1];
    const float* b  = (const float*)d_in[2];
    float* out      = (float*)d_out;

    dim3 grid(4096 / ROWS, N / COLS);   // (256, 2) = 512 blocks, 8 waves each
    tropical_kernel<<<grid, NT, 0, stream>>>(x, w, b, out);
}